// Round 3
// baseline (123.469 us; speedup 1.0000x reference)
//
#include <hip/hip_runtime.h>

#define NB 4096
#define DK 768
#define SCALE_S 0.5295756522f

typedef float f32x4 __attribute__((ext_vector_type(4)));
typedef __bf16 bf16x8 __attribute__((ext_vector_type(8)));

// ---- ws layout (bytes) ----
#define OFF_XB      0u            // 4096*768 bf16 = 6291456
#define OFF_YB      6291456u
#define OFF_ROWPM   12582912u     // 16*4096 f32 (256KB region reserved 512KB)
#define OFF_ROWPS   13107200u
#define OFF_COLPM   13631488u
#define OFF_COLPS   14155776u
#define OFF_LSER    14680064u     // 4096 f32
#define OFF_LSEC    14696448u
#define OFF_BITS    14712832u     // 4096 u32
#define OFF_CSPART  14729216u     // 16*32 int
#define OFF_DOTP    14731264u     // 96 f32
#define OFF_UPART   14731648u     // 32*32*768 f32
#define OFF_VPART   17877376u     // 32*32*768 f32  (end ~21 MB)

static __device__ __forceinline__ unsigned short f2bf(float f) {
  union { float f; unsigned u; } x; x.f = f;
  unsigned r = x.u + 0x7fffu + ((x.u >> 16) & 1u);   // RNE
  return (unsigned short)(r >> 16);
}

static __device__ __forceinline__ void gload16(const void* g, void* l) {
  __builtin_amdgcn_global_load_lds(
      (const __attribute__((address_space(1))) unsigned int*)g,
      (__attribute__((address_space(3))) unsigned int*)l,
      16, 0, 0);
}

// K1: pack label-row bits + per-block column-count partials
__global__ void k_pack(const int* __restrict__ labels, unsigned* __restrict__ bits,
                       int* __restrict__ csPart) {
  __shared__ int cs[32];
  int t = threadIdx.x;
  if (t < 32) cs[t] = 0;
  __syncthreads();
  int i = blockIdx.x * 256 + t;
  const int* row = labels + (size_t)i * 32;
  unsigned b = 0;
#pragma unroll
  for (int j = 0; j < 32; ++j) if (row[j] != 0) b |= (1u << j);
  bits[i] = b;
#pragma unroll
  for (int j = 0; j < 32; ++j) if (b & (1u << j)) atomicAdd(&cs[j], 1);
  __syncthreads();
  if (t < 32) csPart[blockIdx.x * 32 + t] = cs[t];
}

// K3: partial U = mask^T X, V = mask^T Y per 128-row chunk, 16 j's per block.
// jg==0 pass also emits the bf16 conversion of X,Y (fused former k_conv).
__global__ void k_uv(const float* __restrict__ X, const float* __restrict__ Y,
                     const unsigned* __restrict__ bits,
                     float* __restrict__ Up, float* __restrict__ Vp,
                     unsigned short* __restrict__ Xb, unsigned short* __restrict__ Yb) {
  int d = blockIdx.x * 256 + threadIdx.x;   // 0..767
  int chunk = blockIdx.y;                    // 0..31
  int jg = blockIdx.z;                       // 0..1
  float u[16], v[16];
#pragma unroll
  for (int j = 0; j < 16; ++j) { u[j] = 0.f; v[j] = 0.f; }
  int i0 = chunk * 128;
  for (int ii = 0; ii < 128; ++ii) {
    int i = i0 + ii;
    unsigned b = bits[i] >> (jg * 16);
    float x = X[(size_t)i * DK + d];
    float y = Y[(size_t)i * DK + d];
    if (jg == 0) {
      Xb[(size_t)i * DK + d] = f2bf(x);
      Yb[(size_t)i * DK + d] = f2bf(y);
    }
#pragma unroll
    for (int j = 0; j < 16; ++j) {
      bool m = (b >> j) & 1u;
      u[j] += m ? x : 0.f;
      v[j] += m ? y : 0.f;
    }
  }
  size_t base = (size_t)chunk * (32 * DK) + (size_t)jg * (16 * DK);
#pragma unroll
  for (int j = 0; j < 16; ++j) {
    Up[base + j * DK + d] = u[j];
    Vp[base + j * DK + d] = v[j];
  }
}

// K4: 256x256 bf16 MFMA GEMM, BK=32, 4-slot LDS pipeline (depth 3), counted vmcnt,
// T2 swizzle, T5 setprio, fused row/col (max,sumexp) epilogue.
// LDS slot s (shorts): A at s*16384 (256x32), B at s*16384+8192. 4 slots = 128KB.

#define STAGE_A(kt2) do { \
    const int _ss = (kt2) & 3; \
    const unsigned short* _g = gA + (size_t)(kt2) * 32; \
    gload16(_g,                    lds_us + _ss * 16384 + wave * 512); \
    gload16(_g + (size_t)128 * DK, lds_us + _ss * 16384 + 4096 + wave * 512); \
  } while (0)

#define STAGE_B(kt2) do { \
    const int _ss = (kt2) & 3; \
    const unsigned short* _g = gB + (size_t)(kt2) * 32; \
    gload16(_g,                    lds_us + _ss * 16384 + 8192 + wave * 512); \
    gload16(_g + (size_t)128 * DK, lds_us + _ss * 16384 + 12288 + wave * 512); \
  } while (0)

#define TILE(kt1, DOSTAGE) do { \
    const unsigned short* _sb = lds_us + ((kt1) & 3) * 16384; \
    bf16x8 _af[4], _bf[4]; \
    _Pragma("unroll") for (int m = 0; m < 4; ++m) _af[m] = *(const bf16x8*)(_sb + aoff + m * 512); \
    _Pragma("unroll") for (int n = 0; n < 4; ++n) _bf[n] = *(const bf16x8*)(_sb + boff + n * 512); \
    if (DOSTAGE) { STAGE_A((kt1) + 3); } \
    __builtin_amdgcn_s_barrier(); \
    asm volatile("s_waitcnt lgkmcnt(0)" ::: "memory"); \
    __builtin_amdgcn_sched_barrier(0); \
    __builtin_amdgcn_s_setprio(1); \
    _Pragma("unroll") for (int m = 0; m < 4; ++m) \
      _Pragma("unroll") for (int n = 0; n < 4; ++n) \
        acc[m][n] = __builtin_amdgcn_mfma_f32_16x16x32_bf16(_af[m], _bf[n], acc[m][n], 0, 0, 0); \
    __builtin_amdgcn_s_setprio(0); \
    __builtin_amdgcn_s_barrier(); \
    _Pragma("unroll") for (int m = 0; m < 4; ++m) _af[m] = *(const bf16x8*)(_sb + aoff + (m + 4) * 512); \
    if (DOSTAGE) { STAGE_B((kt1) + 3); } \
    __builtin_amdgcn_s_barrier(); \
    asm volatile("s_waitcnt lgkmcnt(0)" ::: "memory"); \
    __builtin_amdgcn_sched_barrier(0); \
    __builtin_amdgcn_s_setprio(1); \
    _Pragma("unroll") for (int m = 0; m < 4; ++m) \
      _Pragma("unroll") for (int n = 0; n < 4; ++n) \
        acc[m + 4][n] = __builtin_amdgcn_mfma_f32_16x16x32_bf16(_af[m], _bf[n], acc[m + 4][n], 0, 0, 0); \
    __builtin_amdgcn_s_setprio(0); \
  } while (0)

__launch_bounds__(512, 2)
__global__ void k_gemm(const unsigned short* __restrict__ Xb,
                       const unsigned short* __restrict__ Yb,
                       float* __restrict__ rowPM, float* __restrict__ rowPS,
                       float* __restrict__ colPM, float* __restrict__ colPS) {
  extern __shared__ unsigned short lds_us[];

  const int t = threadIdx.x;             // 0..511
  const int wave = t >> 6, lane = t & 63;
  const int wr = wave >> 2, wc = wave & 3;

  // bijective XCD-aware swizzle: each XCD gets a 4rb x 8cb sub-grid
  const int bid = blockIdx.x;
  const int xcd = bid & 7, loc = bid >> 3;
  const int rb = (xcd & 3) * 4 + (loc >> 3);
  const int cb = (xcd >> 2) * 8 + (loc & 7);

  // staging: thread t loads 16B; row = t>>2 (+128/round), 16B col-slot pre-swizzled
  const int srow = t >> 2;
  const int sg = (t & 3) ^ ((t >> 3) & 3);            // inverse swizzle on global source
  const unsigned short* gA = Xb + (size_t)(rb * 256 + srow) * DK + sg * 8;
  const unsigned short* gB = Yb + (size_t)(cb * 256 + srow) * DK + sg * 8;

  // fragment read offsets (shorts), swizzled 16B slot
  const int lrow = lane & 15;
  const int eff8 = ((lane >> 4) ^ ((lrow >> 1) & 3)) * 8;
  const int aoff = (wr * 128 + lrow) * 32 + eff8;          // + m*512
  const int boff = 8192 + (wc * 64 + lrow) * 32 + eff8;    // + n*512

  f32x4 acc[8][4];
#pragma unroll
  for (int m = 0; m < 8; ++m)
#pragma unroll
    for (int n = 0; n < 4; ++n) acc[m][n] = (f32x4){0.f, 0.f, 0.f, 0.f};

  // prologue: stage tiles 0,1,2 (12 loads); wait tile0 (8 outstanding allowed)
  STAGE_A(0); STAGE_B(0); STAGE_A(1); STAGE_B(1); STAGE_A(2); STAGE_B(2);
  asm volatile("s_waitcnt vmcnt(8)" ::: "memory");
  __builtin_amdgcn_s_barrier();

  for (int kt = 0; kt < 21; ++kt) {
    TILE(kt, true);
    asm volatile("s_waitcnt vmcnt(8)" ::: "memory");   // tiles <= kt+1 landed
    __builtin_amdgcn_s_barrier();
  }
  TILE(21, false);
  asm volatile("s_waitcnt vmcnt(4)" ::: "memory");
  __builtin_amdgcn_s_barrier();
  TILE(22, false);
  asm volatile("s_waitcnt vmcnt(0)" ::: "memory");
  __builtin_amdgcn_s_barrier();
  TILE(23, false);
  __syncthreads();   // all LDS reads done before reuse

  // ---- epilogue: per-row / per-col (max, sumexp) over this 256x256 tile ----
  // C/D layout: col = lane&15, row = (lane>>4)*4 + reg  [learn_hip m89/m91]
  float* redM  = (float*)lds_us;          // [256][4]
  float* redS  = redM + 1024;             // [256][4]
  float* redM2 = redS + 1024;             // [256][2]
  float* redS2 = redM2 + 512;             // [256][2]

#pragma unroll
  for (int m = 0; m < 8; ++m) {
#pragma unroll
    for (int r = 0; r < 4; ++r) {
      float v0 = SCALE_S * acc[m][0][r];
      float v1 = SCALE_S * acc[m][1][r];
      float v2 = SCALE_S * acc[m][2][r];
      float v3 = SCALE_S * acc[m][3][r];
      float mx = fmaxf(fmaxf(v0, v1), fmaxf(v2, v3));
#pragma unroll
      for (int off = 1; off < 16; off <<= 1) mx = fmaxf(mx, __shfl_xor(mx, off));
      float sm = __expf(v0 - mx) + __expf(v1 - mx) + __expf(v2 - mx) + __expf(v3 - mx);
#pragma unroll
      for (int off = 1; off < 16; off <<= 1) sm += __shfl_xor(sm, off);
      if ((lane & 15) == 0) {
        int row = wr * 128 + m * 16 + (lane >> 4) * 4 + r;
        redM[row * 4 + wc] = mx; redS[row * 4 + wc] = sm;
      }
    }
  }
#pragma unroll
  for (int n = 0; n < 4; ++n) {
    float mx = -3.0e38f;
#pragma unroll
    for (int m = 0; m < 8; ++m)
#pragma unroll
      for (int r = 0; r < 4; ++r) mx = fmaxf(mx, SCALE_S * acc[m][n][r]);
    mx = fmaxf(mx, __shfl_xor(mx, 16));
    mx = fmaxf(mx, __shfl_xor(mx, 32));
    float sm = 0.f;
#pragma unroll
    for (int m = 0; m < 8; ++m)
#pragma unroll
      for (int r = 0; r < 4; ++r) sm += __expf(SCALE_S * acc[m][n][r] - mx);
    sm += __shfl_xor(sm, 16);
    sm += __shfl_xor(sm, 32);
    if (lane < 16) {
      int col = wc * 64 + n * 16 + lane;
      redM2[col * 2 + wr] = mx; redS2[col * 2 + wr] = sm;
    }
  }
  __syncthreads();
  if (t < 256) {
    float M = fmaxf(fmaxf(redM[t * 4 + 0], redM[t * 4 + 1]),
                    fmaxf(redM[t * 4 + 2], redM[t * 4 + 3]));
    float S = 0.f;
#pragma unroll
    for (int k = 0; k < 4; ++k) S += redS[t * 4 + k] * __expf(redM[t * 4 + k] - M);
    rowPM[(size_t)cb * NB + rb * 256 + t] = M;
    rowPS[(size_t)cb * NB + rb * 256 + t] = S;
  } else {
    int c = t - 256;
    float m0 = redM2[c * 2 + 0], m1 = redM2[c * 2 + 1];
    float M = fmaxf(m0, m1);
    float S = redS2[c * 2 + 0] * __expf(m0 - M) + redS2[c * 2 + 1] * __expf(m1 - M);
    colPM[(size_t)rb * NB + cb * 256 + c] = M;
    colPS[(size_t)rb * NB + cb * 256 + c] = S;
  }
}

// K5: fused tail: blocks 0..31 combine lse partials; blocks 32..127 reduce U,V dot
__global__ void k_tail(const float* __restrict__ rowPM, const float* __restrict__ rowPS,
                       const float* __restrict__ colPM, const float* __restrict__ colPS,
                       const float* __restrict__ Up, const float* __restrict__ Vp,
                       float* __restrict__ lse_r, float* __restrict__ lse_c,
                       float* __restrict__ dotPart) {
  int b = blockIdx.x;
  if (b < 32) {
    int g = b * 256 + threadIdx.x;  // 0..8191
    const float* pM; const float* pS; float* out; int i;
    if (g < NB) { pM = rowPM; pS = rowPS; out = lse_r; i = g; }
    else        { pM = colPM; pS = colPS; out = lse_c; i = g - NB; }
    float M = -3.0e38f;
#pragma unroll
    for (int c = 0; c < 16; ++c) M = fmaxf(M, pM[(size_t)c * NB + i]);
    float S = 0.f;
#pragma unroll
    for (int c = 0; c < 16; ++c) S += pS[(size_t)c * NB + i] * __expf(pM[(size_t)c * NB + i] - M);
    out[i] = M + __logf(S);
  } else {
    int e = (b - 32) * 256 + threadIdx.x;  // 0..24575
    float U = 0.f, V = 0.f;
#pragma unroll 8
    for (int c = 0; c < 32; ++c) { U += Up[(size_t)c * 24576 + e]; V += Vp[(size_t)c * 24576 + e]; }
    float p = U * V;
#pragma unroll
    for (int off = 32; off; off >>= 1) p += __shfl_down(p, off);
    __shared__ float red[4];
    if ((threadIdx.x & 63) == 0) red[threadIdx.x >> 6] = p;
    __syncthreads();
    if (threadIdx.x == 0) dotPart[b - 32] = red[0] + red[1] + red[2] + red[3];
  }
}

// K7: finalize scalar loss
__global__ void k_final(const unsigned* __restrict__ bits, const int* __restrict__ csPart,
                        const float* __restrict__ lse_r, const float* __restrict__ lse_c,
                        const float* __restrict__ dotPart, float* __restrict__ out) {
  __shared__ int cs[32];
  __shared__ double red[256];
  int t = threadIdx.x;
  if (t < 32) {
    int s = 0;
    for (int b = 0; b < 16; ++b) s += csPart[b * 32 + t];
    cs[t] = s;
  }
  __syncthreads();
  double acc = 0.0;
  for (int i = t; i < NB; i += 256) {
    unsigned b = bits[i];
    int rw = 0;
#pragma unroll
    for (int j = 0; j < 32; ++j) if (b & (1u << j)) rw += cs[j];
    acc += (double)rw * ((double)lse_r[i] + (double)lse_c[i]);
  }
  if (t < 96) acc -= 2.0 * (double)SCALE_S * (double)dotPart[t];
  red[t] = acc;
  __syncthreads();
  for (int s = 128; s; s >>= 1) {
    if (t < s) red[t] += red[t + s];
    __syncthreads();
  }
  if (t == 0) out[0] = (float)(red[0] / (2.0 * (double)NB * 32.0));
}

extern "C" void kernel_launch(void* const* d_in, const int* in_sizes, int n_in,
                              void* d_out, int out_size, void* d_ws, size_t ws_size,
                              hipStream_t stream) {
  const float* X = (const float*)d_in[0];
  const float* Y = (const float*)d_in[1];
  const int* labels = (const int*)d_in[2];
  char* ws = (char*)d_ws;

  unsigned short* Xb = (unsigned short*)(ws + OFF_XB);
  unsigned short* Yb = (unsigned short*)(ws + OFF_YB);
  float* rowPM = (float*)(ws + OFF_ROWPM);
  float* rowPS = (float*)(ws + OFF_ROWPS);
  float* colPM = (float*)(ws + OFF_COLPM);
  float* colPS = (float*)(ws + OFF_COLPS);
  float* lse_r = (float*)(ws + OFF_LSER);
  float* lse_c = (float*)(ws + OFF_LSEC);
  unsigned* bits = (unsigned*)(ws + OFF_BITS);
  int* csPart = (int*)(ws + OFF_CSPART);
  float* dotPart = (float*)(ws + OFF_DOTP);
  float* Up = (float*)(ws + OFF_UPART);
  float* Vp = (float*)(ws + OFF_VPART);

  // allow 128KB dynamic LDS for k_gemm (idempotent; ignore error)
  (void)hipFuncSetAttribute((const void*)k_gemm,
                            hipFuncAttributeMaxDynamicSharedMemorySize, 131072);

  k_pack<<<16, 256, 0, stream>>>(labels, bits, csPart);
  k_uv<<<dim3(3, 32, 2), 256, 0, stream>>>(X, Y, bits, Up, Vp, Xb, Yb);
  k_gemm<<<256, 512, 131072, stream>>>(Xb, Yb, rowPM, rowPS, colPM, colPS);
  k_tail<<<128, 256, 0, stream>>>(rowPM, rowPS, colPM, colPS, Up, Vp, lse_r, lse_c, dotPart);
  k_final<<<1, 256, 0, stream>>>(bits, csPart, lse_r, lse_c, dotPart, (float*)d_out);
}

// Round 4
// 91.718 us; speedup vs baseline: 1.3462x; 1.3462x over previous
//
#include <hip/hip_runtime.h>

#define NB 4096
#define DK 768
#define SCALE_S 0.5295756522f

typedef float f32x4 __attribute__((ext_vector_type(4)));
typedef __bf16 bf16x8 __attribute__((ext_vector_type(8)));

// ---- ws layout (bytes) ----
#define OFF_XB      0u            // 4096*768 bf16 = 6291456
#define OFF_YB      6291456u
#define OFF_ROWPM   12582912u     // 16*4096 f32 (region reserved 512KB)
#define OFF_ROWPS   13107200u
#define OFF_COLPM   13631488u
#define OFF_COLPS   14155776u
#define OFF_LSER    14680064u     // 4096 f32
#define OFF_LSEC    14696448u
#define OFF_BITS    14712832u     // 4096 u32
#define OFF_CSPART  14729216u     // 16*32 int
#define OFF_DOTP    14731264u     // 96 f32
#define OFF_UPART   14731648u     // 32*32*768 f32
#define OFF_VPART   17877376u     // 32*32*768 f32  (end ~21 MB)

static __device__ __forceinline__ unsigned short f2bf(float f) {
  union { float f; unsigned u; } x; x.f = f;
  unsigned r = x.u + 0x7fffu + ((x.u >> 16) & 1u);   // RNE
  return (unsigned short)(r >> 16);
}

static __device__ __forceinline__ float bf2f(unsigned short h) {
  union { unsigned u; float f; } x; x.u = ((unsigned)h) << 16;
  return x.f;
}

static __device__ __forceinline__ void gload16(const void* g, void* l) {
  __builtin_amdgcn_global_load_lds(
      (const __attribute__((address_space(1))) unsigned int*)g,
      (__attribute__((address_space(3))) unsigned int*)l,
      16, 0, 0);
}

// K1: pack label-row bits + per-block column-count partials
__global__ void k_pack(const int* __restrict__ labels, unsigned* __restrict__ bits,
                       int* __restrict__ csPart) {
  __shared__ int cs[32];
  int t = threadIdx.x;
  if (t < 32) cs[t] = 0;
  __syncthreads();
  int i = blockIdx.x * 256 + t;
  const int* row = labels + (size_t)i * 32;
  unsigned b = 0;
#pragma unroll
  for (int j = 0; j < 32; ++j) if (row[j] != 0) b |= (1u << j);
  bits[i] = b;
#pragma unroll
  for (int j = 0; j < 32; ++j) if (b & (1u << j)) atomicAdd(&cs[j], 1);
  __syncthreads();
  if (t < 32) csPart[blockIdx.x * 32 + t] = cs[t];
}

// K2: fp32 -> bf16 for X and Y
__global__ void k_conv(const float* __restrict__ X, const float* __restrict__ Y,
                       unsigned short* __restrict__ Xb, unsigned short* __restrict__ Yb) {
  const int N4 = (NB * DK) / 4;  // 786432
  for (int idx = blockIdx.x * blockDim.x + threadIdx.x; idx < 2 * N4;
       idx += gridDim.x * blockDim.x) {
    float4 v; unsigned short* dst;
    if (idx < N4) { v = ((const float4*)X)[idx]; dst = Xb + (size_t)idx * 4; }
    else          { v = ((const float4*)Y)[idx - N4]; dst = Yb + (size_t)(idx - N4) * 4; }
    uint2 p;
    p.x = (unsigned)f2bf(v.x) | ((unsigned)f2bf(v.y) << 16);
    p.y = (unsigned)f2bf(v.z) | ((unsigned)f2bf(v.w) << 16);
    *(uint2*)dst = p;
  }
}

// K3: partial U = mask^T X, V = mask^T Y per 128-row chunk, 8 j's per block
// (8 accumulator pairs = proven non-spilling shape; reads bf16 to halve traffic)
__launch_bounds__(256, 2)
__global__ void k_uv(const unsigned short* __restrict__ Xb,
                     const unsigned short* __restrict__ Yb,
                     const unsigned* __restrict__ bits,
                     float* __restrict__ Up, float* __restrict__ Vp) {
  int d = blockIdx.x * 256 + threadIdx.x;   // 0..767
  int chunk = blockIdx.y;                    // 0..31
  int jg = blockIdx.z;                       // 0..3
  float u[8], v[8];
#pragma unroll
  for (int j = 0; j < 8; ++j) { u[j] = 0.f; v[j] = 0.f; }
  int i0 = chunk * 128;
#pragma unroll 4
  for (int ii = 0; ii < 128; ++ii) {
    int i = i0 + ii;
    unsigned b = bits[i] >> (jg * 8);
    float x = bf2f(Xb[(size_t)i * DK + d]);
    float y = bf2f(Yb[(size_t)i * DK + d]);
#pragma unroll
    for (int j = 0; j < 8; ++j) {
      bool m = (b >> j) & 1u;
      u[j] += m ? x : 0.f;
      v[j] += m ? y : 0.f;
    }
  }
  size_t base = (size_t)chunk * (32 * DK) + (size_t)jg * (8 * DK);
#pragma unroll
  for (int j = 0; j < 8; ++j) {
    Up[base + j * DK + d] = u[j];
    Vp[base + j * DK + d] = v[j];
  }
}

// K4: 256x256 bf16 MFMA GEMM, BK=32, 4-slot LDS pipeline (depth 3), counted vmcnt,
// T2 swizzle, T5 setprio, fused row/col (max,sumexp) epilogue.
// LDS slot s (shorts): A at s*16384 (256x32), B at s*16384+8192. 4 slots = 128KB.

#define STAGE_A(kt2) do { \
    const int _ss = (kt2) & 3; \
    const unsigned short* _g = gA + (size_t)(kt2) * 32; \
    gload16(_g,                    lds_us + _ss * 16384 + wave * 512); \
    gload16(_g + (size_t)128 * DK, lds_us + _ss * 16384 + 4096 + wave * 512); \
  } while (0)

#define STAGE_B(kt2) do { \
    const int _ss = (kt2) & 3; \
    const unsigned short* _g = gB + (size_t)(kt2) * 32; \
    gload16(_g,                    lds_us + _ss * 16384 + 8192 + wave * 512); \
    gload16(_g + (size_t)128 * DK, lds_us + _ss * 16384 + 12288 + wave * 512); \
  } while (0)

#define TILE(kt1, DOSTAGE) do { \
    const unsigned short* _sb = lds_us + ((kt1) & 3) * 16384; \
    bf16x8 _af[4], _bf[4]; \
    _Pragma("unroll") for (int m = 0; m < 4; ++m) _af[m] = *(const bf16x8*)(_sb + aoff + m * 512); \
    _Pragma("unroll") for (int n = 0; n < 4; ++n) _bf[n] = *(const bf16x8*)(_sb + boff + n * 512); \
    if (DOSTAGE) { STAGE_A((kt1) + 3); } \
    __builtin_amdgcn_s_barrier(); \
    asm volatile("s_waitcnt lgkmcnt(0)" ::: "memory"); \
    __builtin_amdgcn_sched_barrier(0); \
    __builtin_amdgcn_s_setprio(1); \
    _Pragma("unroll") for (int m = 0; m < 4; ++m) \
      _Pragma("unroll") for (int n = 0; n < 4; ++n) \
        acc[m][n] = __builtin_amdgcn_mfma_f32_16x16x32_bf16(_af[m], _bf[n], acc[m][n], 0, 0, 0); \
    __builtin_amdgcn_s_setprio(0); \
    __builtin_amdgcn_s_barrier(); \
    _Pragma("unroll") for (int m = 0; m < 4; ++m) _af[m] = *(const bf16x8*)(_sb + aoff + (m + 4) * 512); \
    if (DOSTAGE) { STAGE_B((kt1) + 3); } \
    __builtin_amdgcn_s_barrier(); \
    asm volatile("s_waitcnt lgkmcnt(0)" ::: "memory"); \
    __builtin_amdgcn_sched_barrier(0); \
    __builtin_amdgcn_s_setprio(1); \
    _Pragma("unroll") for (int m = 0; m < 4; ++m) \
      _Pragma("unroll") for (int n = 0; n < 4; ++n) \
        acc[m + 4][n] = __builtin_amdgcn_mfma_f32_16x16x32_bf16(_af[m], _bf[n], acc[m + 4][n], 0, 0, 0); \
    __builtin_amdgcn_s_setprio(0); \
  } while (0)

__launch_bounds__(512, 2)
__global__ void k_gemm(const unsigned short* __restrict__ Xb,
                       const unsigned short* __restrict__ Yb,
                       float* __restrict__ rowPM, float* __restrict__ rowPS,
                       float* __restrict__ colPM, float* __restrict__ colPS) {
  extern __shared__ unsigned short lds_us[];

  const int t = threadIdx.x;             // 0..511
  const int wave = t >> 6, lane = t & 63;
  const int wr = wave >> 2, wc = wave & 3;

  // bijective XCD-aware swizzle: each XCD gets a 4rb x 8cb sub-grid
  const int bid = blockIdx.x;
  const int xcd = bid & 7, loc = bid >> 3;
  const int rb = (xcd & 3) * 4 + (loc >> 3);
  const int cb = (xcd >> 2) * 8 + (loc & 7);

  // staging: thread t loads 16B; row = t>>2 (+128/round), 16B col-slot pre-swizzled
  const int srow = t >> 2;
  const int sg = (t & 3) ^ ((t >> 3) & 3);            // inverse swizzle on global source
  const unsigned short* gA = Xb + (size_t)(rb * 256 + srow) * DK + sg * 8;
  const unsigned short* gB = Yb + (size_t)(cb * 256 + srow) * DK + sg * 8;

  // fragment read offsets (shorts), swizzled 16B slot
  const int lrow = lane & 15;
  const int eff8 = ((lane >> 4) ^ ((lrow >> 1) & 3)) * 8;
  const int aoff = (wr * 128 + lrow) * 32 + eff8;          // + m*512
  const int boff = 8192 + (wc * 64 + lrow) * 32 + eff8;    // + n*512

  f32x4 acc[8][4];
#pragma unroll
  for (int m = 0; m < 8; ++m)
#pragma unroll
    for (int n = 0; n < 4; ++n) acc[m][n] = (f32x4){0.f, 0.f, 0.f, 0.f};

  // prologue: stage tiles 0,1,2 (12 loads); wait tile0 (8 outstanding allowed)
  STAGE_A(0); STAGE_B(0); STAGE_A(1); STAGE_B(1); STAGE_A(2); STAGE_B(2);
  asm volatile("s_waitcnt vmcnt(8)" ::: "memory");
  __builtin_amdgcn_s_barrier();

  for (int kt = 0; kt < 21; ++kt) {
    TILE(kt, true);
    asm volatile("s_waitcnt vmcnt(8)" ::: "memory");   // tiles <= kt+1 landed
    __builtin_amdgcn_s_barrier();
  }
  TILE(21, false);
  asm volatile("s_waitcnt vmcnt(4)" ::: "memory");
  __builtin_amdgcn_s_barrier();
  TILE(22, false);
  asm volatile("s_waitcnt vmcnt(0)" ::: "memory");
  __builtin_amdgcn_s_barrier();
  TILE(23, false);
  __syncthreads();   // all LDS reads done before reuse

  // ---- epilogue: per-row / per-col (max, sumexp) over this 256x256 tile ----
  // C/D layout: col = lane&15, row = (lane>>4)*4 + reg  [learn_hip m89/m91]
  float* redM  = (float*)lds_us;          // [256][4]
  float* redS  = redM + 1024;             // [256][4]
  float* redM2 = redS + 1024;             // [256][2]
  float* redS2 = redM2 + 512;             // [256][2]

#pragma unroll
  for (int m = 0; m < 8; ++m) {
#pragma unroll
    for (int r = 0; r < 4; ++r) {
      float v0 = SCALE_S * acc[m][0][r];
      float v1 = SCALE_S * acc[m][1][r];
      float v2 = SCALE_S * acc[m][2][r];
      float v3 = SCALE_S * acc[m][3][r];
      float mx = fmaxf(fmaxf(v0, v1), fmaxf(v2, v3));
#pragma unroll
      for (int off = 1; off < 16; off <<= 1) mx = fmaxf(mx, __shfl_xor(mx, off));
      float sm = __expf(v0 - mx) + __expf(v1 - mx) + __expf(v2 - mx) + __expf(v3 - mx);
#pragma unroll
      for (int off = 1; off < 16; off <<= 1) sm += __shfl_xor(sm, off);
      if ((lane & 15) == 0) {
        int row = wr * 128 + m * 16 + (lane >> 4) * 4 + r;
        redM[row * 4 + wc] = mx; redS[row * 4 + wc] = sm;
      }
    }
  }
#pragma unroll
  for (int n = 0; n < 4; ++n) {
    float mx = -3.0e38f;
#pragma unroll
    for (int m = 0; m < 8; ++m)
#pragma unroll
      for (int r = 0; r < 4; ++r) mx = fmaxf(mx, SCALE_S * acc[m][n][r]);
    mx = fmaxf(mx, __shfl_xor(mx, 16));
    mx = fmaxf(mx, __shfl_xor(mx, 32));
    float sm = 0.f;
#pragma unroll
    for (int m = 0; m < 8; ++m)
#pragma unroll
      for (int r = 0; r < 4; ++r) sm += __expf(SCALE_S * acc[m][n][r] - mx);
    sm += __shfl_xor(sm, 16);
    sm += __shfl_xor(sm, 32);
    if (lane < 16) {
      int col = wc * 64 + n * 16 + lane;
      redM2[col * 2 + wr] = mx; redS2[col * 2 + wr] = sm;
    }
  }
  __syncthreads();
  if (t < 256) {
    float M = fmaxf(fmaxf(redM[t * 4 + 0], redM[t * 4 + 1]),
                    fmaxf(redM[t * 4 + 2], redM[t * 4 + 3]));
    float S = 0.f;
#pragma unroll
    for (int k = 0; k < 4; ++k) S += redS[t * 4 + k] * __expf(redM[t * 4 + k] - M);
    rowPM[(size_t)cb * NB + rb * 256 + t] = M;
    rowPS[(size_t)cb * NB + rb * 256 + t] = S;
  } else {
    int c = t - 256;
    float m0 = redM2[c * 2 + 0], m1 = redM2[c * 2 + 1];
    float M = fmaxf(m0, m1);
    float S = redS2[c * 2 + 0] * __expf(m0 - M) + redS2[c * 2 + 1] * __expf(m1 - M);
    colPM[(size_t)rb * NB + cb * 256 + c] = M;
    colPS[(size_t)rb * NB + cb * 256 + c] = S;
  }
}

// K5: fused tail: blocks 0..31 combine lse partials; blocks 32..127 reduce U,V dot
__global__ void k_tail(const float* __restrict__ rowPM, const float* __restrict__ rowPS,
                       const float* __restrict__ colPM, const float* __restrict__ colPS,
                       const float* __restrict__ Up, const float* __restrict__ Vp,
                       float* __restrict__ lse_r, float* __restrict__ lse_c,
                       float* __restrict__ dotPart) {
  int b = blockIdx.x;
  if (b < 32) {
    int g = b * 256 + threadIdx.x;  // 0..8191
    const float* pM; const float* pS; float* out; int i;
    if (g < NB) { pM = rowPM; pS = rowPS; out = lse_r; i = g; }
    else        { pM = colPM; pS = colPS; out = lse_c; i = g - NB; }
    float M = -3.0e38f;
#pragma unroll
    for (int c = 0; c < 16; ++c) M = fmaxf(M, pM[(size_t)c * NB + i]);
    float S = 0.f;
#pragma unroll
    for (int c = 0; c < 16; ++c) S += pS[(size_t)c * NB + i] * __expf(pM[(size_t)c * NB + i] - M);
    out[i] = M + __logf(S);
  } else {
    int e = (b - 32) * 256 + threadIdx.x;  // 0..24575
    float U = 0.f, V = 0.f;
#pragma unroll 8
    for (int c = 0; c < 32; ++c) { U += Up[(size_t)c * 24576 + e]; V += Vp[(size_t)c * 24576 + e]; }
    float p = U * V;
#pragma unroll
    for (int off = 32; off; off >>= 1) p += __shfl_down(p, off);
    __shared__ float red[4];
    if ((threadIdx.x & 63) == 0) red[threadIdx.x >> 6] = p;
    __syncthreads();
    if (threadIdx.x == 0) dotPart[b - 32] = red[0] + red[1] + red[2] + red[3];
  }
}

// K7: finalize scalar loss
__global__ void k_final(const unsigned* __restrict__ bits, const int* __restrict__ csPart,
                        const float* __restrict__ lse_r, const float* __restrict__ lse_c,
                        const float* __restrict__ dotPart, float* __restrict__ out) {
  __shared__ int cs[32];
  __shared__ double red[256];
  int t = threadIdx.x;
  if (t < 32) {
    int s = 0;
    for (int b = 0; b < 16; ++b) s += csPart[b * 32 + t];
    cs[t] = s;
  }
  __syncthreads();
  double acc = 0.0;
  for (int i = t; i < NB; i += 256) {
    unsigned b = bits[i];
    int rw = 0;
#pragma unroll
    for (int j = 0; j < 32; ++j) if (b & (1u << j)) rw += cs[j];
    acc += (double)rw * ((double)lse_r[i] + (double)lse_c[i]);
  }
  if (t < 96) acc -= 2.0 * (double)SCALE_S * (double)dotPart[t];
  red[t] = acc;
  __syncthreads();
  for (int s = 128; s; s >>= 1) {
    if (t < s) red[t] += red[t + s];
    __syncthreads();
  }
  if (t == 0) out[0] = (float)(red[0] / (2.0 * (double)NB * 32.0));
}

extern "C" void kernel_launch(void* const* d_in, const int* in_sizes, int n_in,
                              void* d_out, int out_size, void* d_ws, size_t ws_size,
                              hipStream_t stream) {
  const float* X = (const float*)d_in[0];
  const float* Y = (const float*)d_in[1];
  const int* labels = (const int*)d_in[2];
  char* ws = (char*)d_ws;

  unsigned short* Xb = (unsigned short*)(ws + OFF_XB);
  unsigned short* Yb = (unsigned short*)(ws + OFF_YB);
  float* rowPM = (float*)(ws + OFF_ROWPM);
  float* rowPS = (float*)(ws + OFF_ROWPS);
  float* colPM = (float*)(ws + OFF_COLPM);
  float* colPS = (float*)(ws + OFF_COLPS);
  float* lse_r = (float*)(ws + OFF_LSER);
  float* lse_c = (float*)(ws + OFF_LSEC);
  unsigned* bits = (unsigned*)(ws + OFF_BITS);
  int* csPart = (int*)(ws + OFF_CSPART);
  float* dotPart = (float*)(ws + OFF_DOTP);
  float* Up = (float*)(ws + OFF_UPART);
  float* Vp = (float*)(ws + OFF_VPART);

  // allow 128KB dynamic LDS for k_gemm (idempotent; ignore error)
  (void)hipFuncSetAttribute((const void*)k_gemm,
                            hipFuncAttributeMaxDynamicSharedMemorySize, 131072);

  k_pack<<<16, 256, 0, stream>>>(labels, bits, csPart);
  k_conv<<<1024, 256, 0, stream>>>(X, Y, Xb, Yb);
  k_uv<<<dim3(3, 32, 4), 256, 0, stream>>>(Xb, Yb, bits, Up, Vp);
  k_gemm<<<256, 512, 131072, stream>>>(Xb, Yb, rowPM, rowPS, colPM, colPS);
  k_tail<<<128, 256, 0, stream>>>(rowPM, rowPS, colPM, colPS, Up, Vp, lse_r, lse_c, dotPart);
  k_final<<<1, 256, 0, stream>>>(bits, csPart, lse_r, lse_c, dotPart, (float*)d_out);
}

// Round 5
// 88.003 us; speedup vs baseline: 1.4030x; 1.0422x over previous
//
#include <hip/hip_runtime.h>

#define NB 4096
#define DK 768
#define SCALE_S 0.5295756522f

typedef float f32x4 __attribute__((ext_vector_type(4)));
typedef __bf16 bf16x8 __attribute__((ext_vector_type(8)));

// ---- ws layout (bytes) ----
#define OFF_XB      0u            // 4096*768 bf16 = 6291456
#define OFF_YB      6291456u
#define OFF_ROWPM   12582912u     // 16*4096 f32 (region reserved 512KB)
#define OFF_ROWPS   13107200u
#define OFF_COLPM   13631488u
#define OFF_COLPS   14155776u
#define OFF_LSER    14680064u     // 4096 f32
#define OFF_LSEC    14696448u
#define OFF_BITS    14712832u     // 4096 u32
#define OFF_CSPART  14729216u     // 16*32 int
#define OFF_DOTP    14731264u     // 96 f32
#define OFF_UPART   14731648u     // 32*32*768 f32
#define OFF_VPART   17877376u     // 32*32*768 f32  (end ~21 MB)

static __device__ __forceinline__ unsigned short f2bf(float f) {
  union { float f; unsigned u; } x; x.f = f;
  unsigned r = x.u + 0x7fffu + ((x.u >> 16) & 1u);   // RNE
  return (unsigned short)(r >> 16);
}

static __device__ __forceinline__ float bf2f(unsigned short h) {
  union { unsigned u; float f; } x; x.u = ((unsigned)h) << 16;
  return x.f;
}

static __device__ __forceinline__ void gload16(const void* g, void* l) {
  __builtin_amdgcn_global_load_lds(
      (const __attribute__((address_space(1))) unsigned int*)g,
      (__attribute__((address_space(3))) unsigned int*)l,
      16, 0, 0);
}

// K1: fused prep. Blocks 0..15: pack label bits + colsum partials.
// Blocks 16..: fp32->bf16 conversion of X and Y (grid-stride).
__global__ void k_prep(const int* __restrict__ labels, unsigned* __restrict__ bits,
                       int* __restrict__ csPart,
                       const float* __restrict__ X, const float* __restrict__ Y,
                       unsigned short* __restrict__ Xb, unsigned short* __restrict__ Yb) {
  int t = threadIdx.x;
  if (blockIdx.x < 16) {
    __shared__ int cs[32];
    if (t < 32) cs[t] = 0;
    __syncthreads();
    int i = blockIdx.x * 256 + t;
    const int* row = labels + (size_t)i * 32;
    unsigned b = 0;
#pragma unroll
    for (int j = 0; j < 32; ++j) if (row[j] != 0) b |= (1u << j);
    bits[i] = b;
#pragma unroll
    for (int j = 0; j < 32; ++j) if (b & (1u << j)) atomicAdd(&cs[j], 1);
    __syncthreads();
    if (t < 32) csPart[blockIdx.x * 32 + t] = cs[t];
  } else {
    const int N4 = (NB * DK) / 4;  // 786432
    const int stride = (gridDim.x - 16) * 256;
    for (int idx = (blockIdx.x - 16) * 256 + t; idx < 2 * N4; idx += stride) {
      float4 v; unsigned short* dst;
      if (idx < N4) { v = ((const float4*)X)[idx]; dst = Xb + (size_t)idx * 4; }
      else          { v = ((const float4*)Y)[idx - N4]; dst = Yb + (size_t)(idx - N4) * 4; }
      uint2 p;
      p.x = (unsigned)f2bf(v.x) | ((unsigned)f2bf(v.y) << 16);
      p.y = (unsigned)f2bf(v.z) | ((unsigned)f2bf(v.w) << 16);
      *(uint2*)dst = p;
    }
  }
}

// K3: partial U = mask^T X, V = mask^T Y per 128-row chunk, 8 j's per block
// (8 accumulator pairs = proven non-spilling shape; reads bf16)
__launch_bounds__(256, 2)
__global__ void k_uv(const unsigned short* __restrict__ Xb,
                     const unsigned short* __restrict__ Yb,
                     const unsigned* __restrict__ bits,
                     float* __restrict__ Up, float* __restrict__ Vp) {
  int d = blockIdx.x * 256 + threadIdx.x;   // 0..767
  int chunk = blockIdx.y;                    // 0..31
  int jg = blockIdx.z;                       // 0..3
  float u[8], v[8];
#pragma unroll
  for (int j = 0; j < 8; ++j) { u[j] = 0.f; v[j] = 0.f; }
  int i0 = chunk * 128;
#pragma unroll 4
  for (int ii = 0; ii < 128; ++ii) {
    int i = i0 + ii;
    unsigned b = bits[i] >> (jg * 8);
    float x = bf2f(Xb[(size_t)i * DK + d]);
    float y = bf2f(Yb[(size_t)i * DK + d]);
#pragma unroll
    for (int j = 0; j < 8; ++j) {
      bool m = (b >> j) & 1u;
      u[j] += m ? x : 0.f;
      v[j] += m ? y : 0.f;
    }
  }
  size_t base = (size_t)chunk * (32 * DK) + (size_t)jg * (8 * DK);
#pragma unroll
  for (int j = 0; j < 8; ++j) {
    Up[base + j * DK + d] = u[j];
    Vp[base + j * DK + d] = v[j];
  }
}

// K4: 256x256 bf16 MFMA GEMM, BK=32, 4-slot LDS (depth-3 prefetch), ONE barrier
// per K-tile, counted vmcnt (never 0 in main loop), compiler-scheduled tile body
// (m97-style fine lgkm interleave), T5 setprio, fused row/col (max,sumexp) epilogue.
// LDS slot s (shorts, stride 16384 = 32KB): A at s*16384 (256x32), B at +8192.

#define STAGE_A(kt2) do { \
    const int _ss = (kt2) & 3; \
    const unsigned short* _g = gA + (size_t)(kt2) * 32; \
    gload16(_g,                    lds_us + _ss * 16384 + wave * 512); \
    gload16(_g + (size_t)128 * DK, lds_us + _ss * 16384 + 4096 + wave * 512); \
  } while (0)

#define STAGE_B(kt2) do { \
    const int _ss = (kt2) & 3; \
    const unsigned short* _g = gB + (size_t)(kt2) * 32; \
    gload16(_g,                    lds_us + _ss * 16384 + 8192 + wave * 512); \
    gload16(_g + (size_t)128 * DK, lds_us + _ss * 16384 + 12288 + wave * 512); \
  } while (0)

// One K-tile body: stage kt+3 early, read 12 frags, 32 MFMA. No internal
// barriers/waits — compiler pipelines ds_read vs MFMA with fine lgkmcnt.
#define BODY(kt1, DOSTAGE) do { \
    asm volatile("" ::: "memory"); \
    if (DOSTAGE) { STAGE_A((kt1) + 3); STAGE_B((kt1) + 3); } \
    const unsigned short* _sb = lds_us + ((kt1) & 3) * 16384; \
    bf16x8 _af[8], _bf[4]; \
    _Pragma("unroll") for (int m = 0; m < 8; ++m) _af[m] = *(const bf16x8*)(_sb + aoff + m * 512); \
    _Pragma("unroll") for (int n = 0; n < 4; ++n) _bf[n] = *(const bf16x8*)(_sb + boff + n * 512); \
    __builtin_amdgcn_s_setprio(1); \
    _Pragma("unroll") for (int m = 0; m < 8; ++m) \
      _Pragma("unroll") for (int n = 0; n < 4; ++n) \
        acc[m][n] = __builtin_amdgcn_mfma_f32_16x16x32_bf16(_af[m], _bf[n], acc[m][n], 0, 0, 0); \
    __builtin_amdgcn_s_setprio(0); \
    asm volatile("" ::: "memory"); \
  } while (0)

__launch_bounds__(512, 2)
__global__ void k_gemm(const unsigned short* __restrict__ Xb,
                       const unsigned short* __restrict__ Yb,
                       float* __restrict__ rowPM, float* __restrict__ rowPS,
                       float* __restrict__ colPM, float* __restrict__ colPS) {
  extern __shared__ unsigned short lds_us[];

  const int t = threadIdx.x;             // 0..511
  const int wave = t >> 6, lane = t & 63;
  const int wr = wave >> 2, wc = wave & 3;

  // bijective XCD-aware swizzle: each XCD gets a 4rb x 8cb sub-grid
  const int bid = blockIdx.x;
  const int xcd = bid & 7, loc = bid >> 3;
  const int rb = (xcd & 3) * 4 + (loc >> 3);
  const int cb = (xcd >> 2) * 8 + (loc & 7);

  // staging: thread t loads 16B; row = t>>2 (+128/round), 16B col-slot pre-swizzled
  const int srow = t >> 2;
  const int sg = (t & 3) ^ ((t >> 3) & 3);            // inverse swizzle on global source
  const unsigned short* gA = Xb + (size_t)(rb * 256 + srow) * DK + sg * 8;
  const unsigned short* gB = Yb + (size_t)(cb * 256 + srow) * DK + sg * 8;

  // fragment read offsets (shorts), swizzled 16B slot
  const int lrow = lane & 15;
  const int eff8 = ((lane >> 4) ^ ((lrow >> 1) & 3)) * 8;
  const int aoff = (wr * 128 + lrow) * 32 + eff8;          // + m*512, m=0..7
  const int boff = 8192 + (wc * 64 + lrow) * 32 + eff8;    // + n*512, n=0..3

  f32x4 acc[8][4];
#pragma unroll
  for (int m = 0; m < 8; ++m)
#pragma unroll
    for (int n = 0; n < 4; ++n) acc[m][n] = (f32x4){0.f, 0.f, 0.f, 0.f};

  // prologue: stage tiles 0,1,2 (12 loads); wait tile0 (8 outstanding allowed)
  STAGE_A(0); STAGE_B(0); STAGE_A(1); STAGE_B(1); STAGE_A(2); STAGE_B(2);
  asm volatile("s_waitcnt vmcnt(8)" ::: "memory");
  __builtin_amdgcn_s_barrier();

  for (int kt = 0; kt < 21; ++kt) {
    BODY(kt, true);
    asm volatile("s_waitcnt vmcnt(8)" ::: "memory");   // tile kt+1 landed
    __builtin_amdgcn_s_barrier();
  }
  BODY(21, false);
  asm volatile("s_waitcnt vmcnt(4)" ::: "memory");
  __builtin_amdgcn_s_barrier();
  BODY(22, false);
  asm volatile("s_waitcnt vmcnt(0)" ::: "memory");
  __builtin_amdgcn_s_barrier();
  BODY(23, false);
  __syncthreads();   // all LDS reads done before reuse

  // ---- epilogue: per-row / per-col (max, sumexp) over this 256x256 tile ----
  // C/D layout: col = lane&15, row = (lane>>4)*4 + reg  [learn_hip m89/m91]
  float* redM  = (float*)lds_us;          // [256][4]
  float* redS  = redM + 1024;             // [256][4]
  float* redM2 = redS + 1024;             // [256][2]
  float* redS2 = redM2 + 512;             // [256][2]

#pragma unroll
  for (int m = 0; m < 8; ++m) {
#pragma unroll
    for (int r = 0; r < 4; ++r) {
      float v0 = SCALE_S * acc[m][0][r];
      float v1 = SCALE_S * acc[m][1][r];
      float v2 = SCALE_S * acc[m][2][r];
      float v3 = SCALE_S * acc[m][3][r];
      float mx = fmaxf(fmaxf(v0, v1), fmaxf(v2, v3));
#pragma unroll
      for (int off = 1; off < 16; off <<= 1) mx = fmaxf(mx, __shfl_xor(mx, off));
      float sm = __expf(v0 - mx) + __expf(v1 - mx) + __expf(v2 - mx) + __expf(v3 - mx);
#pragma unroll
      for (int off = 1; off < 16; off <<= 1) sm += __shfl_xor(sm, off);
      if ((lane & 15) == 0) {
        int row = wr * 128 + m * 16 + (lane >> 4) * 4 + r;
        redM[row * 4 + wc] = mx; redS[row * 4 + wc] = sm;
      }
    }
  }
#pragma unroll
  for (int n = 0; n < 4; ++n) {
    float mx = -3.0e38f;
#pragma unroll
    for (int m = 0; m < 8; ++m)
#pragma unroll
      for (int r = 0; r < 4; ++r) mx = fmaxf(mx, SCALE_S * acc[m][n][r]);
    mx = fmaxf(mx, __shfl_xor(mx, 16));
    mx = fmaxf(mx, __shfl_xor(mx, 32));
    float sm = 0.f;
#pragma unroll
    for (int m = 0; m < 8; ++m)
#pragma unroll
      for (int r = 0; r < 4; ++r) sm += __expf(SCALE_S * acc[m][n][r] - mx);
    sm += __shfl_xor(sm, 16);
    sm += __shfl_xor(sm, 32);
    if (lane < 16) {
      int col = wc * 64 + n * 16 + lane;
      redM2[col * 2 + wr] = mx; redS2[col * 2 + wr] = sm;
    }
  }
  __syncthreads();
  if (t < 256) {
    float M = fmaxf(fmaxf(redM[t * 4 + 0], redM[t * 4 + 1]),
                    fmaxf(redM[t * 4 + 2], redM[t * 4 + 3]));
    float S = 0.f;
#pragma unroll
    for (int k = 0; k < 4; ++k) S += redS[t * 4 + k] * __expf(redM[t * 4 + k] - M);
    rowPM[(size_t)cb * NB + rb * 256 + t] = M;
    rowPS[(size_t)cb * NB + rb * 256 + t] = S;
  } else {
    int c = t - 256;
    float m0 = redM2[c * 2 + 0], m1 = redM2[c * 2 + 1];
    float M = fmaxf(m0, m1);
    float S = redS2[c * 2 + 0] * __expf(m0 - M) + redS2[c * 2 + 1] * __expf(m1 - M);
    colPM[(size_t)rb * NB + cb * 256 + c] = M;
    colPS[(size_t)rb * NB + cb * 256 + c] = S;
  }
}

// K5: fused tail: blocks 0..31 combine lse partials; blocks 32..127 reduce U,V dot
__global__ void k_tail(const float* __restrict__ rowPM, const float* __restrict__ rowPS,
                       const float* __restrict__ colPM, const float* __restrict__ colPS,
                       const float* __restrict__ Up, const float* __restrict__ Vp,
                       float* __restrict__ lse_r, float* __restrict__ lse_c,
                       float* __restrict__ dotPart) {
  int b = blockIdx.x;
  if (b < 32) {
    int g = b * 256 + threadIdx.x;  // 0..8191
    const float* pM; const float* pS; float* out; int i;
    if (g < NB) { pM = rowPM; pS = rowPS; out = lse_r; i = g; }
    else        { pM = colPM; pS = colPS; out = lse_c; i = g - NB; }
    float M = -3.0e38f;
#pragma unroll
    for (int c = 0; c < 16; ++c) M = fmaxf(M, pM[(size_t)c * NB + i]);
    float S = 0.f;
#pragma unroll
    for (int c = 0; c < 16; ++c) S += pS[(size_t)c * NB + i] * __expf(pM[(size_t)c * NB + i] - M);
    out[i] = M + __logf(S);
  } else {
    int e = (b - 32) * 256 + threadIdx.x;  // 0..24575
    float U = 0.f, V = 0.f;
#pragma unroll 8
    for (int c = 0; c < 32; ++c) { U += Up[(size_t)c * 24576 + e]; V += Vp[(size_t)c * 24576 + e]; }
    float p = U * V;
#pragma unroll
    for (int off = 32; off; off >>= 1) p += __shfl_down(p, off);
    __shared__ float red[4];
    if ((threadIdx.x & 63) == 0) red[threadIdx.x >> 6] = p;
    __syncthreads();
    if (threadIdx.x == 0) dotPart[b - 32] = red[0] + red[1] + red[2] + red[3];
  }
}

// K7: finalize scalar loss
__global__ void k_final(const unsigned* __restrict__ bits, const int* __restrict__ csPart,
                        const float* __restrict__ lse_r, const float* __restrict__ lse_c,
                        const float* __restrict__ dotPart, float* __restrict__ out) {
  __shared__ int cs[32];
  __shared__ double red[256];
  int t = threadIdx.x;
  if (t < 32) {
    int s = 0;
    for (int b = 0; b < 16; ++b) s += csPart[b * 32 + t];
    cs[t] = s;
  }
  __syncthreads();
  double acc = 0.0;
  for (int i = t; i < NB; i += 256) {
    unsigned b = bits[i];
    int rw = 0;
#pragma unroll
    for (int j = 0; j < 32; ++j) if (b & (1u << j)) rw += cs[j];
    acc += (double)rw * ((double)lse_r[i] + (double)lse_c[i]);
  }
  if (t < 96) acc -= 2.0 * (double)SCALE_S * (double)dotPart[t];
  red[t] = acc;
  __syncthreads();
  for (int s = 128; s; s >>= 1) {
    if (t < s) red[t] += red[t + s];
    __syncthreads();
  }
  if (t == 0) out[0] = (float)(red[0] / (2.0 * (double)NB * 32.0));
}

extern "C" void kernel_launch(void* const* d_in, const int* in_sizes, int n_in,
                              void* d_out, int out_size, void* d_ws, size_t ws_size,
                              hipStream_t stream) {
  const float* X = (const float*)d_in[0];
  const float* Y = (const float*)d_in[1];
  const int* labels = (const int*)d_in[2];
  char* ws = (char*)d_ws;

  unsigned short* Xb = (unsigned short*)(ws + OFF_XB);
  unsigned short* Yb = (unsigned short*)(ws + OFF_YB);
  float* rowPM = (float*)(ws + OFF_ROWPM);
  float* rowPS = (float*)(ws + OFF_ROWPS);
  float* colPM = (float*)(ws + OFF_COLPM);
  float* colPS = (float*)(ws + OFF_COLPS);
  float* lse_r = (float*)(ws + OFF_LSER);
  float* lse_c = (float*)(ws + OFF_LSEC);
  unsigned* bits = (unsigned*)(ws + OFF_BITS);
  int* csPart = (int*)(ws + OFF_CSPART);
  float* dotPart = (float*)(ws + OFF_DOTP);
  float* Up = (float*)(ws + OFF_UPART);
  float* Vp = (float*)(ws + OFF_VPART);

  // allow 128KB dynamic LDS for k_gemm (idempotent; ignore error)
  (void)hipFuncSetAttribute((const void*)k_gemm,
                            hipFuncAttributeMaxDynamicSharedMemorySize, 131072);

  k_prep<<<528, 256, 0, stream>>>(labels, bits, csPart, X, Y, Xb, Yb);
  k_uv<<<dim3(3, 32, 4), 256, 0, stream>>>(Xb, Yb, bits, Up, Vp);
  k_gemm<<<256, 512, 131072, stream>>>(Xb, Yb, rowPM, rowPS, colPM, colPS);
  k_tail<<<128, 256, 0, stream>>>(rowPM, rowPS, colPM, colPS, Up, Vp, lse_r, lse_c, dotPart);
  k_final<<<1, 256, 0, stream>>>(bits, csPart, lse_r, lse_c, dotPart, (float*)d_out);
}